// Round 2
// baseline (73839.111 us; speedup 1.0000x reference)
//
#include <hip/hip_runtime.h>

typedef _Float16 f16;
typedef _Float16 f16x8 __attribute__((ext_vector_type(8)));
typedef float    f32x4 __attribute__((ext_vector_type(4)));
typedef unsigned long long u64;
typedef unsigned int u32;
typedef u32 u32x4 __attribute__((ext_vector_type(4)));

#define TSEQ 128
#define PRED 10
#define TAGM 0x40004000u
#define N_HARD 8192

union G { u32x4 u; f16x8 h; };

__device__ __forceinline__ float ftanh(float x) {
  float e = __expf(2.0f * x);
  return 1.0f - 2.0f / (e + 1.0f);
}

// 4-bit step tag carried in bit14 of each of the 4 f16 lanes of every u64.
// tanh outputs satisfy |v| < 2 so bit14 (exp MSB) is always 0 in payload.
__device__ __forceinline__ void tag_e(unsigned tg, u32& e0, u32& e1) {
  e0 = ((tg & 1u) << 14) | (((tg >> 1) & 1u) << 30);
  e1 = (((tg >> 2) & 1u) << 14) | (((tg >> 3) & 1u) << 30);
}

struct Ring {
  u64 addr[4];
  u32x4 v[4][2];
};

__device__ __forceinline__ void republish(Ring& r, int rn) {
  for (int i = 0; i < rn; i++) {
    if (r.addr[i]) {
      u64 a = r.addr[i];
      __hip_atomic_store((u64*)(uintptr_t)a,        (((u64)r.v[i][0][1]) << 32) | r.v[i][0][0], __ATOMIC_RELAXED, __HIP_MEMORY_SCOPE_AGENT);
      __hip_atomic_store((u64*)(uintptr_t)(a + 8),  (((u64)r.v[i][0][3]) << 32) | r.v[i][0][2], __ATOMIC_RELAXED, __HIP_MEMORY_SCOPE_AGENT);
      __hip_atomic_store((u64*)(uintptr_t)(a + 16), (((u64)r.v[i][1][1]) << 32) | r.v[i][1][0], __ATOMIC_RELAXED, __HIP_MEMORY_SCOPE_AGENT);
      __hip_atomic_store((u64*)(uintptr_t)(a + 24), (((u64)r.v[i][1][3]) << 32) | r.v[i][1][2], __ATOMIC_RELAXED, __HIP_MEMORY_SCOPE_AGENT);
    }
  }
}

// publish one 16-row-slice worth of this lane: two 16B tagged stores
__device__ __forceinline__ void publish32(u64 addr, u32x4 p0, u32x4 p1, bool slow) {
  if (!slow) {
    *(u32x4*)(uintptr_t)addr = p0;
    *(u32x4*)(uintptr_t)(addr + 16) = p1;
  } else {
    __hip_atomic_store((u64*)(uintptr_t)addr,        (((u64)p0[1]) << 32) | p0[0], __ATOMIC_RELAXED, __HIP_MEMORY_SCOPE_AGENT);
    __hip_atomic_store((u64*)(uintptr_t)(addr + 8),  (((u64)p0[3]) << 32) | p0[2], __ATOMIC_RELAXED, __HIP_MEMORY_SCOPE_AGENT);
    __hip_atomic_store((u64*)(uintptr_t)(addr + 16), (((u64)p1[1]) << 32) | p1[0], __ATOMIC_RELAXED, __HIP_MEMORY_SCOPE_AGENT);
    __hip_atomic_store((u64*)(uintptr_t)(addr + 24), (((u64)p1[3]) << 32) | p1[2], __ATOMIC_RELAXED, __HIP_MEMORY_SCOPE_AGENT);
  }
}

// self-validating poll of 16 x 16B granules (= one full MFMA A-tile per wave).
// fast path: sc0 loads (L1-bypass, L2-serve). fallback: agent atomics + cluster flag.
__device__ __forceinline__ void poll16(u64 base, unsigned tg, G* af,
                                       bool& slow, int* flagp, Ring& ring, int rn) {
  u32 e0, e1;
  tag_e(tg, e0, e1);
  u32x4 g[16];
  unsigned pend = 0xFFFFu;
  int att = 0;
  bool first = true;
  while (true) {
    if (!slow && first) {
      asm volatile(
          "global_load_dwordx4 %0, %16, off sc0\n\t"
          "global_load_dwordx4 %1, %16, off offset:64 sc0\n\t"
          "global_load_dwordx4 %2, %16, off offset:128 sc0\n\t"
          "global_load_dwordx4 %3, %16, off offset:192 sc0\n\t"
          "global_load_dwordx4 %4, %16, off offset:256 sc0\n\t"
          "global_load_dwordx4 %5, %16, off offset:320 sc0\n\t"
          "global_load_dwordx4 %6, %16, off offset:384 sc0\n\t"
          "global_load_dwordx4 %7, %16, off offset:448 sc0\n\t"
          "global_load_dwordx4 %8, %16, off offset:512 sc0\n\t"
          "global_load_dwordx4 %9, %16, off offset:576 sc0\n\t"
          "global_load_dwordx4 %10, %16, off offset:640 sc0\n\t"
          "global_load_dwordx4 %11, %16, off offset:704 sc0\n\t"
          "global_load_dwordx4 %12, %16, off offset:768 sc0\n\t"
          "global_load_dwordx4 %13, %16, off offset:832 sc0\n\t"
          "global_load_dwordx4 %14, %16, off offset:896 sc0\n\t"
          "global_load_dwordx4 %15, %16, off offset:960 sc0\n\t"
          "s_waitcnt vmcnt(0)"
          : "=v"(g[0]), "=v"(g[1]), "=v"(g[2]), "=v"(g[3]),
            "=v"(g[4]), "=v"(g[5]), "=v"(g[6]), "=v"(g[7]),
            "=v"(g[8]), "=v"(g[9]), "=v"(g[10]), "=v"(g[11]),
            "=v"(g[12]), "=v"(g[13]), "=v"(g[14]), "=v"(g[15])
          : "v"(base)
          : "memory");
    } else if (!slow) {
#pragma unroll
      for (int i = 0; i < 16; i++)
        if (pend & (1u << i)) {
          asm volatile("global_load_dwordx4 %0, %1, off sc0\n\ts_waitcnt vmcnt(0)"
                       : "=v"(g[i]) : "v"(base + (u64)(i * 64)) : "memory");
        }
    } else {
#pragma unroll
      for (int i = 0; i < 16; i++)
        if (pend & (1u << i)) {
          u64 lo = __hip_atomic_load((u64*)(uintptr_t)(base + (u64)(i * 64)), __ATOMIC_RELAXED, __HIP_MEMORY_SCOPE_AGENT);
          u64 hi = __hip_atomic_load((u64*)(uintptr_t)(base + (u64)(i * 64) + 8), __ATOMIC_RELAXED, __HIP_MEMORY_SCOPE_AGENT);
          u32x4 t;
          t[0] = (u32)lo; t[1] = (u32)(lo >> 32); t[2] = (u32)hi; t[3] = (u32)(hi >> 32);
          g[i] = t;
        }
    }
    first = false;
#pragma unroll
    for (int i = 0; i < 16; i++)
      if (pend & (1u << i)) {
        if ((((g[i][0] ^ e0) | (g[i][2] ^ e0) | (g[i][1] ^ e1) | (g[i][3] ^ e1)) & TAGM) == 0) {
          u32x4 c = g[i];
          c[0] &= ~TAGM; c[1] &= ~TAGM; c[2] &= ~TAGM; c[3] &= ~TAGM;
          af[i].u = c;
          pend &= ~(1u << i);
        }
      }
    if (!__any(pend != 0)) break;
    att++;
    if (!slow && (((att & 127) == 0) || att > N_HARD)) {
      int f = (att > N_HARD) ? 1
            : __hip_atomic_load(flagp, __ATOMIC_RELAXED, __HIP_MEMORY_SCOPE_AGENT);
      if (f) {
        slow = true;
        __hip_atomic_store(flagp, 1, __ATOMIC_RELAXED, __HIP_MEMORY_SCOPE_AGENT);
        republish(ring, rn);
      }
    }
    __builtin_amdgcn_s_sleep(1);
  }
}

// ---------------- small utility kernels ----------------
__global__ void k_cvt(const float* __restrict__ src, f16* __restrict__ dst, int n) {
  int i = blockIdx.x * blockDim.x + threadIdx.x;
  int stride = gridDim.x * blockDim.x;
  for (; i < n; i += stride) dst[i] = (f16)src[i];
}

__global__ void k_bias(const float* __restrict__ a, const float* __restrict__ b,
                       float* __restrict__ o, int n) {
  int i = blockIdx.x * blockDim.x + threadIdx.x;
  if (i < n) o[i] = a[i] + b[i];
}

// layer-0 input transform: xw0[m][col] = x[m][0:6] @ Wih0[col][0:6] + bias[col]
__global__ __launch_bounds__(256) void k_gemm_x0(
    const float* __restrict__ x, const float* __restrict__ W,
    const float* __restrict__ bias, f16* __restrict__ out) {
  int job = blockIdx.x * 256 + threadIdx.x;  // 131072*64
  int m = job >> 6, cg = job & 63;
  float xv[6];
#pragma unroll
  for (int d = 0; d < 6; d++) xv[d] = x[(size_t)m * 6 + d];
  f16x8 o;
#pragma unroll
  for (int j = 0; j < 8; j++) {
    int col = cg * 8 + j;
    float s = bias[col];
#pragma unroll
    for (int d = 0; d < 6; d++) s += xv[d] * W[col * 6 + d];
    o[j] = (f16)s;
  }
  *(f16x8*)&out[(size_t)m * 512 + cg * 8] = o;
}

// ---------------- input-transform GEMM (layers 1..3) ----------------
__global__ __launch_bounds__(256) void k_gemm_xw(
    const f16* __restrict__ A, const f16* __restrict__ W,
    const float* __restrict__ bias, f16* __restrict__ C) {
  __shared__ f16 As[128 * 72];
  __shared__ f16 Bs[256 * 72];
  const int tid = threadIdx.x;
  const int w = tid >> 6, lane = tid & 63;
  const int wm = w >> 1, wn = w & 1;
  const int q = lane >> 4, l15 = lane & 15;
  const int m0 = blockIdx.x * 128;
  const int n0 = blockIdx.y * 256;

  f32x4 acc[4][8];
  const f32x4 zero = {0.f, 0.f, 0.f, 0.f};
#pragma unroll
  for (int i = 0; i < 4; i++)
#pragma unroll
    for (int j = 0; j < 8; j++) acc[i][j] = zero;

  for (int k0 = 0; k0 < 512; k0 += 64) {
    __syncthreads();
#pragma unroll
    for (int i = 0; i < 4; i++) {
      int ch = tid + 256 * i; int r = ch >> 3, kc = ch & 7;
      *(f16x8*)&As[r * 72 + kc * 8] = *(const f16x8*)&A[(size_t)(m0 + r) * 512 + k0 + kc * 8];
    }
#pragma unroll
    for (int i = 0; i < 8; i++) {
      int ch = tid + 256 * i; int r = ch >> 3, kc = ch & 7;
      *(f16x8*)&Bs[r * 72 + kc * 8] = *(const f16x8*)&W[(size_t)(n0 + r) * 512 + k0 + kc * 8];
    }
    __syncthreads();
#pragma unroll
    for (int kk = 0; kk < 2; kk++) {
      f16x8 af[4], bf[8];
#pragma unroll
      for (int mt = 0; mt < 4; mt++)
        af[mt] = *(const f16x8*)&As[(wm * 64 + mt * 16 + l15) * 72 + kk * 32 + q * 8];
#pragma unroll
      for (int nt = 0; nt < 8; nt++)
        bf[nt] = *(const f16x8*)&Bs[(wn * 128 + nt * 16 + l15) * 72 + kk * 32 + q * 8];
#pragma unroll
      for (int mt = 0; mt < 4; mt++)
#pragma unroll
        for (int nt = 0; nt < 8; nt++)
          acc[mt][nt] = __builtin_amdgcn_mfma_f32_16x16x32_f16(af[mt], bf[nt], acc[mt][nt], 0, 0, 0);
    }
  }
#pragma unroll
  for (int mt = 0; mt < 4; mt++)
#pragma unroll
    for (int nt = 0; nt < 8; nt++)
#pragma unroll
      for (int r = 0; r < 4; r++) {
        int mg = m0 + wm * 64 + mt * 16 + q * 4 + r;
        int ng = n0 + wn * 128 + nt * 16 + l15;
        C[(size_t)mg * 512 + ng] = (f16)(acc[mt][nt][r] + bias[ng]);
      }
}

// ---------------- encoder recurrence: 1 wave / 64 cols, no barriers ----------
// grid 512 x 64: c = blk&63 (16 batch rows), sub = blk>>6 (64 cols).
// cluster of 8 waves exchanges h through same-XCD L2 (plain store / sc0 load)
// with agent-scope sticky fallback.
__global__ __launch_bounds__(64) void k_enc_rec(
    const f16* __restrict__ xw, const f16* __restrict__ Whh,
    f16* __restrict__ out_h, float* __restrict__ out_f,
    f16* __restrict__ hT, f16* __restrict__ hx, int* __restrict__ flags) {
  __shared__ f16 sc[16 * 64];
  const int lane = threadIdx.x;
  const int q = lane >> 4, l15 = lane & 15;
  const int c = blockIdx.x & 63, sub = blockIdx.x >> 6;
  const int row0 = c * 16;
  const int ncol0 = sub * 64;
  int* flagp = flags + c;
  const u64 hx_b = (u64)(uintptr_t)hx;

  // register-resident Whh fragments for this wave's 64 cols
  f16x8 Bfr[4][16];
#pragma unroll
  for (int nt = 0; nt < 4; nt++) {
    int ng = ncol0 + nt * 16 + l15;
#pragma unroll
    for (int kk = 0; kk < 16; kk++)
      Bfr[nt][kk] = *(const f16x8*)&Whh[(size_t)ng * 512 + kk * 32 + q * 8];
  }

  bool slow = false;
  Ring ring;
  ring.addr[0] = 0;

  // transposed-store lane mapping
  const int trow = lane & 15, tqg = lane >> 4;

  f16 xcur[16], xnxt[16];
#pragma unroll
  for (int nt = 0; nt < 4; nt++)
#pragma unroll
    for (int r = 0; r < 4; r++)
      xcur[nt * 4 + r] = xw[((size_t)(row0 + q * 4 + r) * TSEQ + 0) * 512 + ncol0 + nt * 16 + l15];

  for (int t = 0; t < TSEQ; t++) {
    const f32x4 zero = {0.f, 0.f, 0.f, 0.f};
    f32x4 acc[4] = {zero, zero, zero, zero};

    int fl = 0;
    if (t) {
      if (!slow) fl = __hip_atomic_load(flagp, __ATOMIC_RELAXED, __HIP_MEMORY_SCOPE_AGENT);
      // poll h_{t-1}: granules are the MFMA A-fragments directly
      G af[16];
      const int pr = (t - 1) & 1;
      u64 base = hx_b + (u64)(((size_t)pr * 64 + c) * 8192 + (size_t)l15 * 512 + q * 8) * 2;
      poll16(base, (unsigned)(((t - 1) >> 1) & 15), af, slow, flagp, ring, 1);
      if (fl && !slow) { slow = true; republish(ring, 1); }
      // prefetch next step's xw under compute/publish
      if (t + 1 < TSEQ) {
#pragma unroll
        for (int nt = 0; nt < 4; nt++)
#pragma unroll
          for (int r = 0; r < 4; r++)
            xnxt[nt * 4 + r] = xw[((size_t)(row0 + q * 4 + r) * TSEQ + (t + 1)) * 512 + ncol0 + nt * 16 + l15];
      }
#pragma unroll
      for (int kk = 0; kk < 16; kk++) {
        f16x8 a = af[kk].h;
        acc[0] = __builtin_amdgcn_mfma_f32_16x16x32_f16(a, Bfr[0][kk], acc[0], 0, 0, 0);
        acc[1] = __builtin_amdgcn_mfma_f32_16x16x32_f16(a, Bfr[1][kk], acc[1], 0, 0, 0);
        acc[2] = __builtin_amdgcn_mfma_f32_16x16x32_f16(a, Bfr[2][kk], acc[2], 0, 0, 0);
        acc[3] = __builtin_amdgcn_mfma_f32_16x16x32_f16(a, Bfr[3][kk], acc[3], 0, 0, 0);
      }
    } else {
#pragma unroll
      for (int nt = 0; nt < 4; nt++)
#pragma unroll
        for (int r = 0; r < 4; r++)
          xnxt[nt * 4 + r] = xw[((size_t)(row0 + q * 4 + r) * TSEQ + 1) * 512 + ncol0 + nt * 16 + l15];
    }

    float hv[4][4];
#pragma unroll
    for (int nt = 0; nt < 4; nt++)
#pragma unroll
      for (int r = 0; r < 4; r++) {
        hv[nt][r] = ftanh(acc[nt][r] + (float)xcur[nt * 4 + r]);
        sc[(q * 4 + r) * 64 + nt * 16 + l15] = (f16)hv[nt][r];
      }
    asm volatile("s_waitcnt lgkmcnt(0)" ::: "memory");
    u32x4 v0 = *(const u32x4*)&sc[trow * 64 + tqg * 16];
    u32x4 v1 = *(const u32x4*)&sc[trow * 64 + tqg * 16 + 8];

    // publish first (peers wait on it)
    if (t < TSEQ - 1) {
      u32 e0, e1;
      tag_e((unsigned)((t >> 1) & 15), e0, e1);
      u32x4 tor; tor[0] = e0; tor[1] = e1; tor[2] = e0; tor[3] = e1;
      u32x4 p0 = v0 | tor, p1 = v1 | tor;
      u64 addr = hx_b + (u64)(((size_t)(t & 1) * 64 + c) * 8192 + (size_t)trow * 512 + ncol0 + tqg * 16) * 2;
      publish32(addr, p0, p1, slow);
      ring.addr[0] = addr;
      ring.v[0][0] = p0; ring.v[0][1] = p1;
    }

    // bulk outputs (off the sync critical path)
    if (out_h) {
      size_t ob = ((size_t)(row0 + trow) * TSEQ + t) * 512 + ncol0 + tqg * 16;
      *(u32x4*)&out_h[ob] = v0;
      *(u32x4*)&out_h[ob + 8] = v1;
    }
    if (out_f) {
#pragma unroll
      for (int nt = 0; nt < 4; nt++)
#pragma unroll
        for (int r = 0; r < 4; r++)
          out_f[((size_t)(row0 + q * 4 + r) * TSEQ + t) * 512 + ncol0 + nt * 16 + l15] = hv[nt][r];
    }
    if (t == TSEQ - 1) {
      size_t hb = (size_t)(row0 + trow) * 512 + ncol0 + tqg * 16;
      *(u32x4*)&hT[hb] = v0;
      *(u32x4*)&hT[hb + 8] = v1;
      break;
    }
#pragma unroll
    for (int i = 0; i < 16; i++) xcur[i] = xnxt[i];
  }
}

// ---------------- decoder: 1 wave / 64 cols, no barriers ----------------
__global__ __launch_bounds__(64) void k_dec_rec(
    const f16* __restrict__ Wih, const f16* __restrict__ Whh,
    const float* __restrict__ decB, const f16* __restrict__ hT,
    f16* __restrict__ hstate, f16* __restrict__ dec_out, int* __restrict__ flags) {
  __shared__ f16 sc[16 * 64];
  const int lane = threadIdx.x;
  const int q = lane >> 4, l15 = lane & 15;
  const int c = blockIdx.x & 63, sub = blockIdx.x >> 6;
  const int row0 = c * 16;
  const int ncol0 = sub * 64;
  int* flagp = flags + c;
  const u64 hs_b = (u64)(uintptr_t)hstate;
  const size_t LSZ = (size_t)1024 * 512;
  const int trow = lane & 15, tqg = lane >> 4;

  bool slow = false;
  Ring ring;
  ring.addr[0] = ring.addr[1] = ring.addr[2] = ring.addr[3] = 0;

  auto plain16 = [&](const f16* src, G* af) {
    const char* p = (const char*)src + ((size_t)(row0 + l15) * 512 + q * 8) * 2;
#pragma unroll
    for (int kk = 0; kk < 16; kk++) af[kk].u = *(const u32x4*)(p + kk * 64);
  };

  for (int s = 0; s < PRED; s++) {
    int wb = (s + 1) & 1, rb = s & 1;
    unsigned tgp = (unsigned)(((s - 1) >> 1) & 15);
    unsigned tgc = (unsigned)((s >> 1) & 15);
    for (int l = 0; l < 4; l++) {
      const int n = s * 4 + l;
      const bool last = (s == PRED - 1) && (l == 3);
      const bool haspoll = !(s == 0 && l == 0);

      int fl = 0;
      if (haspoll && !slow)
        fl = __hip_atomic_load(flagp, __ATOMIC_RELAXED, __HIP_MEMORY_SCOPE_AGENT);

      G ax[16], ah[16];
      // x operand
      if (s == 0 && l == 0) {
        plain16(hT + 3 * LSZ, ax);
      } else {
        int slotx; unsigned tgx;
        if (l == 0) { slotx = rb * 4 + 3; tgx = tgp; }
        else        { slotx = wb * 4 + (l - 1); tgx = (s == 0) ? 0u : tgc; }
        u64 base = hs_b + (u64)(((size_t)slotx * 64 + c) * 8192 + (size_t)l15 * 512 + q * 8) * 2;
        poll16(base, tgx, ax, slow, flagp, ring, 4);
      }
      // h operand
      if (s == 0) {
        plain16(hT + (size_t)l * LSZ, ah);
      } else {
        u64 base = hs_b + (u64)(((size_t)(rb * 4 + l) * 64 + c) * 8192 + (size_t)l15 * 512 + q * 8) * 2;
        poll16(base, tgp, ah, slow, flagp, ring, 4);
      }
      if (fl && !slow) { slow = true; republish(ring, 4); }

      const f32x4 zero = {0.f, 0.f, 0.f, 0.f};
      f32x4 acc[4] = {zero, zero, zero, zero};
      const f16* Wl = Wih + (size_t)l * 262144;
      const f16* Ul = Whh + (size_t)l * 262144;
      const f16* wp0 = &Wl[(size_t)(ncol0 + 0 * 16 + l15) * 512 + q * 8];
      const f16* wp1 = &Wl[(size_t)(ncol0 + 1 * 16 + l15) * 512 + q * 8];
      const f16* wp2 = &Wl[(size_t)(ncol0 + 2 * 16 + l15) * 512 + q * 8];
      const f16* wp3 = &Wl[(size_t)(ncol0 + 3 * 16 + l15) * 512 + q * 8];
#pragma unroll
      for (int kk = 0; kk < 16; kk++) {
        f16x8 a = ax[kk].h;
        acc[0] = __builtin_amdgcn_mfma_f32_16x16x32_f16(a, *(const f16x8*)(wp0 + kk * 32), acc[0], 0, 0, 0);
        acc[1] = __builtin_amdgcn_mfma_f32_16x16x32_f16(a, *(const f16x8*)(wp1 + kk * 32), acc[1], 0, 0, 0);
        acc[2] = __builtin_amdgcn_mfma_f32_16x16x32_f16(a, *(const f16x8*)(wp2 + kk * 32), acc[2], 0, 0, 0);
        acc[3] = __builtin_amdgcn_mfma_f32_16x16x32_f16(a, *(const f16x8*)(wp3 + kk * 32), acc[3], 0, 0, 0);
      }
      const f16* up0 = &Ul[(size_t)(ncol0 + 0 * 16 + l15) * 512 + q * 8];
      const f16* up1 = &Ul[(size_t)(ncol0 + 1 * 16 + l15) * 512 + q * 8];
      const f16* up2 = &Ul[(size_t)(ncol0 + 2 * 16 + l15) * 512 + q * 8];
      const f16* up3 = &Ul[(size_t)(ncol0 + 3 * 16 + l15) * 512 + q * 8];
#pragma unroll
      for (int kk = 0; kk < 16; kk++) {
        f16x8 a = ah[kk].h;
        acc[0] = __builtin_amdgcn_mfma_f32_16x16x32_f16(a, *(const f16x8*)(up0 + kk * 32), acc[0], 0, 0, 0);
        acc[1] = __builtin_amdgcn_mfma_f32_16x16x32_f16(a, *(const f16x8*)(up1 + kk * 32), acc[1], 0, 0, 0);
        acc[2] = __builtin_amdgcn_mfma_f32_16x16x32_f16(a, *(const f16x8*)(up2 + kk * 32), acc[2], 0, 0, 0);
        acc[3] = __builtin_amdgcn_mfma_f32_16x16x32_f16(a, *(const f16x8*)(up3 + kk * 32), acc[3], 0, 0, 0);
      }

      float bv[4];
#pragma unroll
      for (int nt = 0; nt < 4; nt++) bv[nt] = decB[l * 512 + ncol0 + nt * 16 + l15];
#pragma unroll
      for (int nt = 0; nt < 4; nt++)
#pragma unroll
        for (int r = 0; r < 4; r++)
          sc[(q * 4 + r) * 64 + nt * 16 + l15] = (f16)ftanh(acc[nt][r] + bv[nt]);
      asm volatile("s_waitcnt lgkmcnt(0)" ::: "memory");
      u32x4 v0 = *(const u32x4*)&sc[trow * 64 + tqg * 16];
      u32x4 v1 = *(const u32x4*)&sc[trow * 64 + tqg * 16 + 8];

      if (!last) {
        u32 e0, e1;
        tag_e(tgc, e0, e1);
        u32x4 tor; tor[0] = e0; tor[1] = e1; tor[2] = e0; tor[3] = e1;
        u32x4 p0 = v0 | tor, p1 = v1 | tor;
        u64 addr = hs_b + (u64)(((size_t)(wb * 4 + l) * 64 + c) * 8192 + (size_t)trow * 512 + ncol0 + tqg * 16) * 2;
        publish32(addr, p0, p1, slow);
        ring.addr[n & 3] = addr;
        ring.v[n & 3][0] = p0; ring.v[n & 3][1] = p1;
      }

      if (l == 3) {
        size_t ob = ((size_t)(row0 + trow) * PRED + s) * 512 + ncol0 + tqg * 16;
        *(u32x4*)&dec_out[ob] = v0;
        *(u32x4*)&dec_out[ob + 8] = v1;
      }
    }
  }
}

// ---------------- final FC ----------------
__global__ __launch_bounds__(256) void k_fc(
    const f16* __restrict__ dec_out, const float* __restrict__ fcW,
    const float* __restrict__ fcb, float* __restrict__ out) {
  __shared__ float Wl[6 * 512];
  __shared__ float bl[8];
  int tid = threadIdx.x;
  for (int i = tid; i < 3072; i += 256) Wl[i] = fcW[i];
  if (tid < 6) bl[tid] = fcb[tid];
  __syncthreads();
  int g = blockIdx.x * 256 + tid;  // 0..10239
  const f16* row = dec_out + (size_t)g * 512;
  float acc[6] = {0, 0, 0, 0, 0, 0};
  for (int kc = 0; kc < 64; kc++) {
    f16x8 xv = *(const f16x8*)&row[kc * 8];
#pragma unroll
    for (int j = 0; j < 8; j++) {
      float xf = (float)xv[j];
#pragma unroll
      for (int o = 0; o < 6; o++) acc[o] += xf * Wl[o * 512 + kc * 8 + j];
    }
  }
#pragma unroll
  for (int o = 0; o < 6; o++) out[(size_t)g * 6 + o] = acc[o] + bl[o];
}

extern "C" void kernel_launch(void* const* d_in, const int* in_sizes, int n_in,
                              void* d_out, int out_size, void* d_ws, size_t ws_size,
                              hipStream_t stream) {
  const float* x      = (const float*)d_in[0];
  const float* Wih0   = (const float*)d_in[1];
  const float* eWih32 = (const float*)d_in[2];
  const float* eWhh32 = (const float*)d_in[3];
  const float* ebih   = (const float*)d_in[4];
  const float* ebhh   = (const float*)d_in[5];
  const float* dWih32 = (const float*)d_in[6];
  const float* dWhh32 = (const float*)d_in[7];
  const float* dbih   = (const float*)d_in[8];
  const float* dbhh   = (const float*)d_in[9];
  const float* fcW    = (const float*)d_in[10];
  const float* fcb    = (const float*)d_in[11];
  float* outp = (float*)d_out;

  char* ws = (char*)d_ws;
  size_t off = 0;
  auto alloc = [&](size_t bytes) { void* p = ws + off; off += (bytes + 255) & ~255ULL; return p; };
  f16* outA   = (f16*)alloc((size_t)131072 * 512 * 2);
  f16* xwB    = (f16*)alloc((size_t)131072 * 512 * 2);
  f16* eWih   = (f16*)alloc((size_t)3 * 262144 * 2);
  f16* eWhh   = (f16*)alloc((size_t)4 * 262144 * 2);
  f16* dWih   = (f16*)alloc((size_t)4 * 262144 * 2);
  f16* dWhh   = (f16*)alloc((size_t)4 * 262144 * 2);
  float* encB = (float*)alloc(2048 * 4);
  float* decB = (float*)alloc(2048 * 4);
  f16* hT     = (f16*)alloc((size_t)4 * 1024 * 512 * 2);
  f16* hstate = (f16*)alloc((size_t)8 * 1024 * 512 * 2);
  f16* hx     = (f16*)alloc((size_t)2 * 1024 * 512 * 2);
  f16* dec_o  = (f16*)alloc((size_t)1024 * 10 * 512 * 2);
  int* flags  = (int*)alloc(5 * 64 * 4);

  // arm exchange buffers: 0xFF -> tag 15, never the first expected tag
  hipMemsetAsync(hx, 0xFF, (size_t)2 * 1024 * 512 * 2, stream);
  hipMemsetAsync(hstate, 0xFF, (size_t)8 * 1024 * 512 * 2, stream);
  hipMemsetAsync(flags, 0, 5 * 64 * 4, stream);

  k_cvt<<<512, 256, 0, stream>>>(eWih32, eWih, 3 * 262144);
  k_cvt<<<512, 256, 0, stream>>>(eWhh32, eWhh, 4 * 262144);
  k_cvt<<<512, 256, 0, stream>>>(dWih32, dWih, 4 * 262144);
  k_cvt<<<512, 256, 0, stream>>>(dWhh32, dWhh, 4 * 262144);
  k_bias<<<8, 256, 0, stream>>>(ebih, ebhh, encB, 2048);
  k_bias<<<8, 256, 0, stream>>>(dbih, dbhh, decB, 2048);

  // layer 0 input transform (K=6), then 4 identical recurrence layers
  k_gemm_x0<<<32768, 256, 0, stream>>>(x, Wih0, encB, xwB);
  for (int l = 0; l < 4; l++) {
    if (l > 0)
      k_gemm_xw<<<dim3(1024, 2), 256, 0, stream>>>(outA, eWih + (size_t)(l - 1) * 262144,
                                                   encB + l * 512, xwB);
    f16* oh = (l < 3) ? outA : nullptr;
    float* of = (l == 3) ? outp : nullptr;
    k_enc_rec<<<512, 64, 0, stream>>>(xwB, eWhh + (size_t)l * 262144, oh, of,
                                      hT + (size_t)l * 524288, hx, flags + l * 64);
  }
  k_dec_rec<<<512, 64, 0, stream>>>(dWih, dWhh, decB, hT, hstate, dec_o, flags + 4 * 64);
  k_fc<<<40, 256, 0, stream>>>(dec_o, fcW, fcb, outp + (size_t)1024 * 128 * 512);
}

// Round 4
// 4874.738 us; speedup vs baseline: 15.1473x; 15.1473x over previous
//
#include <hip/hip_runtime.h>

typedef _Float16 f16;
typedef _Float16 f16x8 __attribute__((ext_vector_type(8)));
typedef float    f32x4 __attribute__((ext_vector_type(4)));
typedef unsigned long long u64;

#define TSEQ 128
#define PRED 10

// ---------------- small utility kernels ----------------
__global__ void k_cvt(const float* __restrict__ src, f16* __restrict__ dst, int n) {
  int i = blockIdx.x * blockDim.x + threadIdx.x;
  int stride = gridDim.x * blockDim.x;
  for (; i < n; i += stride) dst[i] = (f16)src[i];
}

__global__ void k_bias(const float* __restrict__ a, const float* __restrict__ b,
                       float* __restrict__ o, int n) {
  int i = blockIdx.x * blockDim.x + threadIdx.x;
  if (i < n) o[i] = a[i] + b[i];
}

// ---------------- wavefront-pipelined encoder ----------------
// grid 1024: bid = c*16 + sub*4 + layer.  Each 16-block cluster (one c, all
// layers+subs) is bid-contiguous -> prefix-of-clusters completes independently
// (no global co-residency requirement).  layer = bid&3 => under round-robin
// dispatch each XCD hosts one layer's weights (Whh + Wih slice, ~1.5 MB -> L2).
// Within a layer: proven counter protocol (publish h, vmcnt0, barrier, arrive;
// spin; gather agent-scope).  Across layers: producer computes xw_{t-1} =
// h_{t-1} @ Wih^{l+1} from its gathered LDS tile, publishes into a 16-slot
// ring with produce/consume counters (same drain-then-flag idiom).
__global__ __launch_bounds__(256, 4) void k_enc_wave(
    const float* __restrict__ x, const float* __restrict__ Wih0,
    const f16* __restrict__ eWih, const float* __restrict__ encB,
    const f16* __restrict__ eWhh, float* __restrict__ out_f,
    f16* __restrict__ hT, f16* __restrict__ hx, f16* __restrict__ xwring,
    int* __restrict__ ctr, int* __restrict__ pf, int* __restrict__ cp) {
  __shared__ f16 As[16 * 520];
  __shared__ float xs[16][8];
  const int tid = threadIdx.x;
  const int w = tid >> 6, lane = tid & 63, q = lane >> 4, l15 = lane & 15;
  const int bid = blockIdx.x;
  const int layer = bid & 3, sub = (bid >> 2) & 3, c = bid >> 4;
  const int row0 = c * 16, ncol0 = sub * 128 + w * 32;
  const int is_l0 = (layer == 0), is_top = (layer == 3);
  int* myctr = ctr + (layer * 64 + c) * 32;
  const f16* Whh = eWhh + (size_t)layer * 262144;
  f16* myhx = hx + (size_t)layer * (2 * 64 * 8192);
  f16* myhT = hT + (size_t)layer * ((size_t)1024 * 512);  // FIX: per-layer slab

  // consumer side (layer >= 1): interface layer-1
  const int ci = is_l0 ? 0 : (layer - 1);
  u64* crng = (u64*)(xwring + (size_t)ci * 64 * 16 * 8192);
  int* cpf = pf + ((ci * 64 + c) * 4 + sub) * 8;
  int* ccp = cp + ((ci * 64 + c) * 4 + sub) * 8;
  // producer side (layer < 3): interface layer
  u64* prng = (u64*)(xwring + (size_t)layer * 64 * 16 * 8192);
  int* ppf = pf + ((layer * 64 + c) * 4 + sub) * 8;
  int* pcp = cp + ((layer * 64 + c) * 4 + sub) * 8;
  const f16* Wt = eWih + (size_t)layer * 262144;

  // register-resident-ish Whh fragments for this wave's 32 cols
  f16x8 Bfr[2][16];
#pragma unroll
  for (int t2 = 0; t2 < 2; t2++) {
    int ng = ncol0 + t2 * 16 + l15;
#pragma unroll
    for (int kk = 0; kk < 16; kk++)
      Bfr[t2][kk] = *(const f16x8*)&Whh[(size_t)ng * 512 + kk * 32 + q * 8];
  }

  float w0[2][6]; float b0[2];
  if (is_l0) {
#pragma unroll
    for (int t2 = 0; t2 < 2; t2++) {
      int ng = ncol0 + t2 * 16 + l15;
#pragma unroll
      for (int d = 0; d < 6; d++) w0[t2][d] = Wih0[ng * 6 + d];
      b0[t2] = encB[ng];
    }
  }
  float tb[2] = {0.f, 0.f};
  if (!is_top) {
    tb[0] = encB[(layer + 1) * 512 + ncol0 + l15];
    tb[1] = encB[(layer + 1) * 512 + ncol0 + 16 + l15];
  }

  for (int i = tid; i < 16 * 520; i += 256) As[i] = (f16)0.0f;
  if (is_l0 && tid < 96) xs[tid / 6][tid % 6] = x[(size_t)(row0 + tid / 6) * TSEQ * 6 + tid % 6];
  __syncthreads();

  for (int t = 0; t < TSEQ; t++) {
    const int p = t & 1;

    // (B) recurrence MFMA on h_{t-1} (As; zeros at t=0)
    const f32x4 zero = {0.f, 0.f, 0.f, 0.f};
    f32x4 acc0 = zero, acc1 = zero;
#pragma unroll
    for (int kk = 0; kk < 16; kk++) {
      f16x8 a = *(const f16x8*)&As[l15 * 520 + kk * 32 + q * 8];
      acc0 = __builtin_amdgcn_mfma_f32_16x16x32_f16(a, Bfr[0][kk], acc0, 0, 0, 0);
      acc1 = __builtin_amdgcn_mfma_f32_16x16x32_f16(a, Bfr[1][kk], acc1, 0, 0, 0);
    }

    // (A) input term: ring consume (hidden under the MFMAs above in issue order)
    f16 xwr[2][4];
    if (!is_l0) {
      while (__hip_atomic_load(cpf, __ATOMIC_RELAXED, __HIP_MEMORY_SCOPE_AGENT) < t + 1)
        __builtin_amdgcn_s_sleep(1);
      u64* rb = crng + ((size_t)c * 16 + (t & 15)) * 2048;
      union { u64 u; f16 h[4]; } a0, a1;
      a0.u = __hip_atomic_load(rb + (size_t)(ncol0 + l15) * 4 + q, __ATOMIC_RELAXED, __HIP_MEMORY_SCOPE_AGENT);
      a1.u = __hip_atomic_load(rb + (size_t)(ncol0 + 16 + l15) * 4 + q, __ATOMIC_RELAXED, __HIP_MEMORY_SCOPE_AGENT);
#pragma unroll
      for (int r = 0; r < 4; r++) { xwr[0][r] = a0.h[r]; xwr[1][r] = a1.h[r]; }
    }

    // (C) tanh + pack
    float hv[2][4];
    union { u64 u; f16 h4[4]; } pk[2];
#pragma unroll
    for (int t2 = 0; t2 < 2; t2++) {
      f32x4 accv = t2 ? acc1 : acc0;
#pragma unroll
      for (int r = 0; r < 4; r++) {
        int m = q * 4 + r;
        float pre;
        if (is_l0) {
          float xwv = b0[t2];
#pragma unroll
          for (int d = 0; d < 6; d++) xwv += xs[m][d] * w0[t2][d];
          pre = accv[r] + xwv;
        } else {
          pre = accv[r] + (float)xwr[t2][r];
        }
        hv[t2][r] = tanhf(pre);
        pk[t2].h4[r] = (f16)hv[t2][r];
      }
    }

    // (D) publish h_t + arrive (layers 0..2 publish every t incl. 127 for the
    // epilogue transform; layer 3 only t<127, exactly like the baseline)
    const bool pub = (t < TSEQ - 1) || !is_top;
    if (pub) {
#pragma unroll
      for (int t2 = 0; t2 < 2; t2++) {
        int ng = ncol0 + t2 * 16 + l15;
        __hip_atomic_store(
            (u64*)&myhx[(((size_t)p * 64 + c) * 512 + ng) * 16 + q * 4],
            pk[t2].u, __ATOMIC_RELAXED, __HIP_MEMORY_SCOPE_AGENT);
      }
      __builtin_amdgcn_s_waitcnt(0);
      __syncthreads();
      if (tid == 0) {
        __hip_atomic_fetch_add(myctr, 1, __ATOMIC_RELAXED, __HIP_MEMORY_SCOPE_AGENT);
        if (!is_l0)
          __hip_atomic_store(ccp, t + 1, __ATOMIC_RELAXED, __HIP_MEMORY_SCOPE_AGENT);
      }
    }

    // (E) outputs
    if (is_top) {
#pragma unroll
      for (int t2 = 0; t2 < 2; t2++) {
        int ng = ncol0 + t2 * 16 + l15;
#pragma unroll
        for (int r = 0; r < 4; r++)
          out_f[((size_t)(row0 + q * 4 + r) * TSEQ + t) * 512 + ng] = hv[t2][r];
      }
    }
    if (t == TSEQ - 1) {
#pragma unroll
      for (int t2 = 0; t2 < 2; t2++) {
        int ng = ncol0 + t2 * 16 + l15;
#pragma unroll
        for (int r = 0; r < 4; r++)
          myhT[(size_t)(row0 + q * 4 + r) * 512 + ng] = pk[t2].h4[r];
      }
    }

    // (F) transform: xw_{t-1} = h_{t-1} @ Wih^{l+1} from As, publish to ring
    if (!is_top && t >= 1) {
      if (t >= 17)
        while (__hip_atomic_load(pcp, __ATOMIC_RELAXED, __HIP_MEMORY_SCOPE_AGENT) < t - 16)
          __builtin_amdgcn_s_sleep(1);
      f32x4 xa0 = zero, xa1 = zero;
#pragma unroll
      for (int kk = 0; kk < 16; kk++) {
        f16x8 a = *(const f16x8*)&As[l15 * 520 + kk * 32 + q * 8];
        f16x8 bv0 = *(const f16x8*)&Wt[(size_t)(ncol0 + l15) * 512 + kk * 32 + q * 8];
        f16x8 bv1 = *(const f16x8*)&Wt[(size_t)(ncol0 + 16 + l15) * 512 + kk * 32 + q * 8];
        xa0 = __builtin_amdgcn_mfma_f32_16x16x32_f16(a, bv0, xa0, 0, 0, 0);
        xa1 = __builtin_amdgcn_mfma_f32_16x16x32_f16(a, bv1, xa1, 0, 0, 0);
      }
      union { u64 u; f16 h4[4]; } qk[2];
#pragma unroll
      for (int r = 0; r < 4; r++) {
        qk[0].h4[r] = (f16)(xa0[r] + tb[0]);
        qk[1].h4[r] = (f16)(xa1[r] + tb[1]);
      }
      u64* rb = prng + ((size_t)c * 16 + ((t - 1) & 15)) * 2048;
      __hip_atomic_store(rb + (size_t)(ncol0 + l15) * 4 + q, qk[0].u, __ATOMIC_RELAXED, __HIP_MEMORY_SCOPE_AGENT);
      __hip_atomic_store(rb + (size_t)(ncol0 + 16 + l15) * 4 + q, qk[1].u, __ATOMIC_RELAXED, __HIP_MEMORY_SCOPE_AGENT);
      __builtin_amdgcn_s_waitcnt(0);
      __syncthreads();
      if (tid == 0)
        __hip_atomic_store(ppf, t, __ATOMIC_RELAXED, __HIP_MEMORY_SCOPE_AGENT);
    }

    if (t == TSEQ - 1) break;

    // (G) gather h_t, rebuild As
    if (tid == 0) {
      int target = 4 * (t + 1);
      while (__hip_atomic_load(myctr, __ATOMIC_RELAXED, __HIP_MEMORY_SCOPE_AGENT) < target)
        __builtin_amdgcn_s_sleep(1);
    }
    __syncthreads();
    {
      u64 v[8];
#pragma unroll
      for (int cc = 0; cc < 2; cc++) {
        int col = tid * 2 + cc;
        const u64* bp = (const u64*)&myhx[(((size_t)p * 64 + c) * 512 + col) * 16];
#pragma unroll
        for (int j = 0; j < 4; j++)
          v[cc * 4 + j] = __hip_atomic_load(bp + j, __ATOMIC_RELAXED, __HIP_MEMORY_SCOPE_AGENT);
      }
      union { u64 u[4]; f16 h[16]; } un0, un1;
      un0.u[0] = v[0]; un0.u[1] = v[1]; un0.u[2] = v[2]; un0.u[3] = v[3];
      un1.u[0] = v[4]; un1.u[1] = v[5]; un1.u[2] = v[6]; un1.u[3] = v[7];
#pragma unroll
      for (int k = 0; k < 16; k++) {
        union { f16 h2[2]; unsigned int u; } pw;
        pw.h2[0] = un0.h[k]; pw.h2[1] = un1.h[k];
        *(unsigned int*)&As[k * 520 + tid * 2] = pw.u;
      }
    }
    if (is_l0 && tid < 96)
      xs[tid / 6][tid % 6] = x[((size_t)(row0 + tid / 6) * TSEQ + (t + 1)) * 6 + tid % 6];
    __syncthreads();
  }

  // epilogue (layers 0..2): gather h_127 and publish xw_127 (slot 15)
  if (!is_top) {
    if (tid == 0) {
      while (__hip_atomic_load(myctr, __ATOMIC_RELAXED, __HIP_MEMORY_SCOPE_AGENT) < 4 * TSEQ)
        __builtin_amdgcn_s_sleep(1);
    }
    __syncthreads();
    {
      u64 v[8];
#pragma unroll
      for (int cc = 0; cc < 2; cc++) {
        int col = tid * 2 + cc;
        const u64* bp = (const u64*)&myhx[(((size_t)1 * 64 + c) * 512 + col) * 16];
#pragma unroll
        for (int j = 0; j < 4; j++)
          v[cc * 4 + j] = __hip_atomic_load(bp + j, __ATOMIC_RELAXED, __HIP_MEMORY_SCOPE_AGENT);
      }
      union { u64 u[4]; f16 h[16]; } un0, un1;
      un0.u[0] = v[0]; un0.u[1] = v[1]; un0.u[2] = v[2]; un0.u[3] = v[3];
      un1.u[0] = v[4]; un1.u[1] = v[5]; un1.u[2] = v[6]; un1.u[3] = v[7];
#pragma unroll
      for (int k = 0; k < 16; k++) {
        union { f16 h2[2]; unsigned int u; } pw;
        pw.h2[0] = un0.h[k]; pw.h2[1] = un1.h[k];
        *(unsigned int*)&As[k * 520 + tid * 2] = pw.u;
      }
    }
    __syncthreads();
    while (__hip_atomic_load(pcp, __ATOMIC_RELAXED, __HIP_MEMORY_SCOPE_AGENT) < TSEQ - 16)
      __builtin_amdgcn_s_sleep(1);
    const f32x4 zero = {0.f, 0.f, 0.f, 0.f};
    f32x4 xa0 = zero, xa1 = zero;
#pragma unroll
    for (int kk = 0; kk < 16; kk++) {
      f16x8 a = *(const f16x8*)&As[l15 * 520 + kk * 32 + q * 8];
      f16x8 bv0 = *(const f16x8*)&Wt[(size_t)(ncol0 + l15) * 512 + kk * 32 + q * 8];
      f16x8 bv1 = *(const f16x8*)&Wt[(size_t)(ncol0 + 16 + l15) * 512 + kk * 32 + q * 8];
      xa0 = __builtin_amdgcn_mfma_f32_16x16x32_f16(a, bv0, xa0, 0, 0, 0);
      xa1 = __builtin_amdgcn_mfma_f32_16x16x32_f16(a, bv1, xa1, 0, 0, 0);
    }
    union { u64 u; f16 h4[4]; } qk[2];
#pragma unroll
    for (int r = 0; r < 4; r++) {
      qk[0].h4[r] = (f16)(xa0[r] + tb[0]);
      qk[1].h4[r] = (f16)(xa1[r] + tb[1]);
    }
    u64* rb = prng + ((size_t)c * 16 + 15) * 2048;
    __hip_atomic_store(rb + (size_t)(ncol0 + l15) * 4 + q, qk[0].u, __ATOMIC_RELAXED, __HIP_MEMORY_SCOPE_AGENT);
    __hip_atomic_store(rb + (size_t)(ncol0 + 16 + l15) * 4 + q, qk[1].u, __ATOMIC_RELAXED, __HIP_MEMORY_SCOPE_AGENT);
    __builtin_amdgcn_s_waitcnt(0);
    __syncthreads();
    if (tid == 0)
      __hip_atomic_store(ppf, TSEQ, __ATOMIC_RELAXED, __HIP_MEMORY_SCOPE_AGENT);
  }
}

// ---------------- decoder (proven baseline, counter protocol) ----------------
__global__ __launch_bounds__(256) void k_dec_rec(
    const f16* __restrict__ Wih, const f16* __restrict__ Whh,
    const float* __restrict__ decB, const f16* __restrict__ hT,
    f16* __restrict__ hstate, f16* __restrict__ dec_out, int* __restrict__ ctr) {
  __shared__ f16 xb[16 * 520];
  __shared__ f16 hb[16 * 520];
  const int tid = threadIdx.x;
  const int w = tid >> 6, lane = tid & 63, q = lane >> 4, l15 = lane & 15;
  const int c = blockIdx.x >> 2, sub = blockIdx.x & 3;
  const int row0 = c * 16;
  const int ncol0 = sub * 128 + w * 32;
  int* myctr = ctr + c * 32;
  const size_t LSZ = (size_t)1024 * 512;

  auto load_rm = [&](f16* dst, const f16* src) {
#pragma unroll
    for (int i = 0; i < 4; i++) {
      int idx = tid + 256 * i; int m = idx >> 6, kc = idx & 63;
      *(f16x8*)&dst[m * 520 + kc * 8] = *(const f16x8*)&src[(size_t)(row0 + m) * 512 + kc * 8];
    }
  };
  auto load_cm = [&](f16* dst, int buf) {
    u64 v[8];
#pragma unroll
    for (int cc = 0; cc < 2; cc++) {
      int col = tid * 2 + cc;
      const u64* bp = (const u64*)&hstate[(((size_t)buf * 64 + c) * 512 + col) * 16];
#pragma unroll
      for (int j = 0; j < 4; j++)
        v[cc * 4 + j] = __hip_atomic_load(bp + j, __ATOMIC_RELAXED, __HIP_MEMORY_SCOPE_AGENT);
    }
    union { u64 u[4]; f16 h[16]; } un0, un1;
    un0.u[0] = v[0]; un0.u[1] = v[1]; un0.u[2] = v[2]; un0.u[3] = v[3];
    un1.u[0] = v[4]; un1.u[1] = v[5]; un1.u[2] = v[6]; un1.u[3] = v[7];
#pragma unroll
    for (int k = 0; k < 16; k++) {
      union { f16 h2[2]; unsigned int u; } pw;
      pw.h2[0] = un0.h[k]; pw.h2[1] = un1.h[k];
      *(unsigned int*)&dst[k * 520 + tid * 2] = pw.u;
    }
  };

  for (int s = 0; s < PRED; s++) {
    int wb = (s + 1) & 1, rb = s & 1;
    for (int l = 0; l < 4; l++) {
      const bool last = (s == PRED - 1) && (l == 3);
      if (l == 0) {
        if (s == 0) load_rm(xb, hT + 3 * LSZ);
        else load_cm(xb, rb * 4 + 3);
      } else {
        load_cm(xb, wb * 4 + (l - 1));
      }
      if (s == 0) load_rm(hb, hT + (size_t)l * LSZ);
      else load_cm(hb, rb * 4 + l);
      __syncthreads();

      const f32x4 zero = {0.f, 0.f, 0.f, 0.f};
      f32x4 acc0 = zero, acc1 = zero;
      const f16* Wl = Wih + (size_t)l * 512 * 512;
      const f16* Ul = Whh + (size_t)l * 512 * 512;
      int ng0 = ncol0 + l15, ng1 = ncol0 + 16 + l15;
#pragma unroll
      for (int kk = 0; kk < 16; kk++) {
        f16x8 a = *(const f16x8*)&xb[l15 * 520 + kk * 32 + q * 8];
        f16x8 bv0 = *(const f16x8*)&Wl[(size_t)ng0 * 512 + kk * 32 + q * 8];
        f16x8 bv1 = *(const f16x8*)&Wl[(size_t)ng1 * 512 + kk * 32 + q * 8];
        acc0 = __builtin_amdgcn_mfma_f32_16x16x32_f16(a, bv0, acc0, 0, 0, 0);
        acc1 = __builtin_amdgcn_mfma_f32_16x16x32_f16(a, bv1, acc1, 0, 0, 0);
      }
#pragma unroll
      for (int kk = 0; kk < 16; kk++) {
        f16x8 a = *(const f16x8*)&hb[l15 * 520 + kk * 32 + q * 8];
        f16x8 bv0 = *(const f16x8*)&Ul[(size_t)ng0 * 512 + kk * 32 + q * 8];
        f16x8 bv1 = *(const f16x8*)&Ul[(size_t)ng1 * 512 + kk * 32 + q * 8];
        acc0 = __builtin_amdgcn_mfma_f32_16x16x32_f16(a, bv0, acc0, 0, 0, 0);
        acc1 = __builtin_amdgcn_mfma_f32_16x16x32_f16(a, bv1, acc1, 0, 0, 0);
      }

      int obuf = wb * 4 + l;
      union { u64 u; f16 h4[4]; } pk[2];
#pragma unroll
      for (int t2 = 0; t2 < 2; t2++) {
        f32x4 accv = t2 ? acc1 : acc0;
        int ng = ncol0 + t2 * 16 + l15;
#pragma unroll
        for (int r = 0; r < 4; r++)
          pk[t2].h4[r] = (f16)tanhf(accv[r] + decB[l * 512 + ng]);
      }

      if (!last) {
#pragma unroll
        for (int t2 = 0; t2 < 2; t2++) {
          int ng = ncol0 + t2 * 16 + l15;
          __hip_atomic_store(
              (u64*)&hstate[(((size_t)obuf * 64 + c) * 512 + ng) * 16 + q * 4],
              pk[t2].u, __ATOMIC_RELAXED, __HIP_MEMORY_SCOPE_AGENT);
        }
        __builtin_amdgcn_s_waitcnt(0);
        __syncthreads();
        if (tid == 0)
          __hip_atomic_fetch_add(myctr, 1, __ATOMIC_RELAXED, __HIP_MEMORY_SCOPE_AGENT);
      }

      if (l == 3) {
#pragma unroll
        for (int t2 = 0; t2 < 2; t2++) {
          int ng = ncol0 + t2 * 16 + l15;
#pragma unroll
          for (int r = 0; r < 4; r++)
            dec_out[((size_t)(row0 + q * 4 + r) * PRED + s) * 512 + ng] = pk[t2].h4[r];
        }
      }

      if (!last) {
        if (tid == 0) {
          int target = 4 * (s * 4 + l + 1);
          while (__hip_atomic_load(myctr, __ATOMIC_RELAXED, __HIP_MEMORY_SCOPE_AGENT) < target)
            __builtin_amdgcn_s_sleep(1);
        }
        __syncthreads();
      }
    }
  }
}

// ---------------- final FC ----------------
__global__ __launch_bounds__(256) void k_fc(
    const f16* __restrict__ dec_out, const float* __restrict__ fcW,
    const float* __restrict__ fcb, float* __restrict__ out) {
  __shared__ float Wl[6 * 512];
  __shared__ float bl[8];
  int tid = threadIdx.x;
  for (int i = tid; i < 3072; i += 256) Wl[i] = fcW[i];
  if (tid < 6) bl[tid] = fcb[tid];
  __syncthreads();
  int g = blockIdx.x * 256 + tid;  // 0..10239
  const f16* row = dec_out + (size_t)g * 512;
  float acc[6] = {0, 0, 0, 0, 0, 0};
  for (int kc = 0; kc < 64; kc++) {
    f16x8 xv = *(const f16x8*)&row[kc * 8];
#pragma unroll
    for (int j = 0; j < 8; j++) {
      float xf = (float)xv[j];
#pragma unroll
      for (int o = 0; o < 6; o++) acc[o] += xf * Wl[o * 512 + kc * 8 + j];
    }
  }
#pragma unroll
  for (int o = 0; o < 6; o++) out[(size_t)g * 6 + o] = acc[o] + bl[o];
}

extern "C" void kernel_launch(void* const* d_in, const int* in_sizes, int n_in,
                              void* d_out, int out_size, void* d_ws, size_t ws_size,
                              hipStream_t stream) {
  const float* x      = (const float*)d_in[0];
  const float* Wih0   = (const float*)d_in[1];
  const float* eWih32 = (const float*)d_in[2];
  const float* eWhh32 = (const float*)d_in[3];
  const float* ebih   = (const float*)d_in[4];
  const float* ebhh   = (const float*)d_in[5];
  const float* dWih32 = (const float*)d_in[6];
  const float* dWhh32 = (const float*)d_in[7];
  const float* dbih   = (const float*)d_in[8];
  const float* dbhh   = (const float*)d_in[9];
  const float* fcW    = (const float*)d_in[10];
  const float* fcb    = (const float*)d_in[11];
  float* outp = (float*)d_out;

  char* ws = (char*)d_ws;
  size_t off = 0;
  auto alloc = [&](size_t bytes) { void* p = ws + off; off += (bytes + 255) & ~255ULL; return p; };
  f16* eWih   = (f16*)alloc((size_t)3 * 262144 * 2);
  f16* eWhh   = (f16*)alloc((size_t)4 * 262144 * 2);
  f16* dWih   = (f16*)alloc((size_t)4 * 262144 * 2);
  f16* dWhh   = (f16*)alloc((size_t)4 * 262144 * 2);
  float* encB = (float*)alloc(2048 * 4);
  float* decB = (float*)alloc(2048 * 4);
  f16* hT     = (f16*)alloc((size_t)4 * 1024 * 512 * 2);
  f16* hstate = (f16*)alloc((size_t)8 * 1024 * 512 * 2);
  f16* hx     = (f16*)alloc((size_t)4 * 2 * 64 * 8192 * 2);
  f16* xwring = (f16*)alloc((size_t)3 * 64 * 16 * 8192 * 2);
  f16* dec_o  = (f16*)alloc((size_t)1024 * 10 * 512 * 2);
  // sync block: encoder ctr (4*64*32) + dec ctr (64*32) + pf + cp
  int* ctrE   = (int*)alloc(4 * 64 * 32 * 4);
  int* ctrD   = (int*)alloc(64 * 32 * 4);
  int* pfA    = (int*)alloc(3 * 64 * 4 * 8 * 4);
  int* cpA    = (int*)alloc(3 * 64 * 4 * 8 * 4);

  size_t syncsz = (char*)(cpA + 3 * 64 * 4 * 8) - (char*)ctrE;
  hipMemsetAsync(ctrE, 0, syncsz, stream);

  k_cvt<<<512, 256, 0, stream>>>(eWih32, eWih, 3 * 262144);
  k_cvt<<<512, 256, 0, stream>>>(eWhh32, eWhh, 4 * 262144);
  k_cvt<<<512, 256, 0, stream>>>(dWih32, dWih, 4 * 262144);
  k_cvt<<<512, 256, 0, stream>>>(dWhh32, dWhh, 4 * 262144);
  k_bias<<<8, 256, 0, stream>>>(ebih, ebhh, encB, 2048);
  k_bias<<<8, 256, 0, stream>>>(dbih, dbhh, decB, 2048);

  // wavefront-pipelined encoder: all 4 layers in one launch
  k_enc_wave<<<1024, 256, 0, stream>>>(x, Wih0, eWih, encB, eWhh, outp, hT, hx,
                                       xwring, ctrE, pfA, cpA);
  k_dec_rec<<<256, 256, 0, stream>>>(dWih, dWhh, decB, hT, hstate, dec_o, ctrD);
  k_fc<<<40, 256, 0, stream>>>(dec_o, fcW, fcb, outp + (size_t)1024 * 128 * 512);
}

// Round 5
// 3750.475 us; speedup vs baseline: 19.6879x; 1.2998x over previous
//
#include <hip/hip_runtime.h>

typedef _Float16 f16;
typedef _Float16 f16x8 __attribute__((ext_vector_type(8)));
typedef float    f32x4 __attribute__((ext_vector_type(4)));
typedef unsigned long long u64;

#define TSEQ 128
#define PRED 10

// ---------------- small utility kernels ----------------
__global__ void k_cvt(const float* __restrict__ src, f16* __restrict__ dst, int n) {
  int i = blockIdx.x * blockDim.x + threadIdx.x;
  int stride = gridDim.x * blockDim.x;
  for (; i < n; i += stride) dst[i] = (f16)src[i];
}

__global__ void k_bias(const float* __restrict__ a, const float* __restrict__ b,
                       float* __restrict__ o, int n) {
  int i = blockIdx.x * blockDim.x + threadIdx.x;
  if (i < n) o[i] = a[i] + b[i];
}

// ---------------- wavefront-pipelined encoder ----------------
// grid 1024: bid = c*16 + sub*4 + layer.  Each 16-block cluster (one c, all
// layers+subs) is bid-contiguous -> prefix-of-clusters completes independently
// (no global co-residency requirement; with ~2 blocks/CU resident the grid
// runs as ~2 generations of whole clusters).  layer = bid&3 => under
// round-robin dispatch each XCD hosts one layer's weights (~1.5 MB -> L2).
// Within a layer: proven counter protocol (publish h, vmcnt0, barrier, arrive;
// spin; gather agent-scope).  Across layers: producer computes xw_{t-1} =
// h_{t-1} @ Wih^{l+1} from its gathered LDS tile, publishes into a 16-slot
// ring with produce/consume counters (same drain-then-flag idiom).
// NOTE: launch_bounds (256,2) — NOT (256,4): the Bfr[2][16] weight cache is
// 128 VGPRs; a 128-VGPR cap forces it to scratch (measured: 7.4 GB spill
// traffic/dispatch, 8x slowdown). 2 waves/EU -> 256-VGPR budget, regs stay.
__global__ __launch_bounds__(256, 2) void k_enc_wave(
    const float* __restrict__ x, const float* __restrict__ Wih0,
    const f16* __restrict__ eWih, const float* __restrict__ encB,
    const f16* __restrict__ eWhh, float* __restrict__ out_f,
    f16* __restrict__ hT, f16* __restrict__ hx, f16* __restrict__ xwring,
    int* __restrict__ ctr, int* __restrict__ pf, int* __restrict__ cp) {
  __shared__ f16 As[16 * 520];
  __shared__ float xs[16][8];
  const int tid = threadIdx.x;
  const int w = tid >> 6, lane = tid & 63, q = lane >> 4, l15 = lane & 15;
  const int bid = blockIdx.x;
  const int layer = bid & 3, sub = (bid >> 2) & 3, c = bid >> 4;
  const int row0 = c * 16, ncol0 = sub * 128 + w * 32;
  const int is_l0 = (layer == 0), is_top = (layer == 3);
  int* myctr = ctr + (layer * 64 + c) * 32;
  const f16* Whh = eWhh + (size_t)layer * 262144;
  f16* myhx = hx + (size_t)layer * (2 * 64 * 8192);
  f16* myhT = hT + (size_t)layer * ((size_t)1024 * 512);

  // consumer side (layer >= 1): interface layer-1
  const int ci = is_l0 ? 0 : (layer - 1);
  u64* crng = (u64*)(xwring + (size_t)ci * 64 * 16 * 8192);
  int* cpf = pf + ((ci * 64 + c) * 4 + sub) * 8;
  int* ccp = cp + ((ci * 64 + c) * 4 + sub) * 8;
  // producer side (layer < 3): interface layer
  u64* prng = (u64*)(xwring + (size_t)layer * 64 * 16 * 8192);
  int* ppf = pf + ((layer * 64 + c) * 4 + sub) * 8;
  int* pcp = cp + ((layer * 64 + c) * 4 + sub) * 8;
  const f16* Wt = eWih + (size_t)layer * 262144;

  // register-resident Whh fragments for this wave's 32 cols (128 VGPRs)
  f16x8 Bfr[2][16];
#pragma unroll
  for (int t2 = 0; t2 < 2; t2++) {
    int ng = ncol0 + t2 * 16 + l15;
#pragma unroll
    for (int kk = 0; kk < 16; kk++)
      Bfr[t2][kk] = *(const f16x8*)&Whh[(size_t)ng * 512 + kk * 32 + q * 8];
  }

  float w0[2][6]; float b0[2];
  if (is_l0) {
#pragma unroll
    for (int t2 = 0; t2 < 2; t2++) {
      int ng = ncol0 + t2 * 16 + l15;
#pragma unroll
      for (int d = 0; d < 6; d++) w0[t2][d] = Wih0[ng * 6 + d];
      b0[t2] = encB[ng];
    }
  }
  float tb[2] = {0.f, 0.f};
  if (!is_top) {
    tb[0] = encB[(layer + 1) * 512 + ncol0 + l15];
    tb[1] = encB[(layer + 1) * 512 + ncol0 + 16 + l15];
  }

  for (int i = tid; i < 16 * 520; i += 256) As[i] = (f16)0.0f;
  if (is_l0 && tid < 96) xs[tid / 6][tid % 6] = x[(size_t)(row0 + tid / 6) * TSEQ * 6 + tid % 6];
  __syncthreads();

  for (int t = 0; t < TSEQ; t++) {
    const int p = t & 1;

    // (B) recurrence MFMA on h_{t-1} (As; zeros at t=0)
    const f32x4 zero = {0.f, 0.f, 0.f, 0.f};
    f32x4 acc0 = zero, acc1 = zero;
#pragma unroll
    for (int kk = 0; kk < 16; kk++) {
      f16x8 a = *(const f16x8*)&As[l15 * 520 + kk * 32 + q * 8];
      acc0 = __builtin_amdgcn_mfma_f32_16x16x32_f16(a, Bfr[0][kk], acc0, 0, 0, 0);
      acc1 = __builtin_amdgcn_mfma_f32_16x16x32_f16(a, Bfr[1][kk], acc1, 0, 0, 0);
    }

    // (A) input term: ring consume (hidden under the MFMAs above in issue order)
    f16 xwr[2][4];
    if (!is_l0) {
      while (__hip_atomic_load(cpf, __ATOMIC_RELAXED, __HIP_MEMORY_SCOPE_AGENT) < t + 1)
        __builtin_amdgcn_s_sleep(1);
      u64* rb = crng + ((size_t)c * 16 + (t & 15)) * 2048;
      union { u64 u; f16 h[4]; } a0, a1;
      a0.u = __hip_atomic_load(rb + (size_t)(ncol0 + l15) * 4 + q, __ATOMIC_RELAXED, __HIP_MEMORY_SCOPE_AGENT);
      a1.u = __hip_atomic_load(rb + (size_t)(ncol0 + 16 + l15) * 4 + q, __ATOMIC_RELAXED, __HIP_MEMORY_SCOPE_AGENT);
#pragma unroll
      for (int r = 0; r < 4; r++) { xwr[0][r] = a0.h[r]; xwr[1][r] = a1.h[r]; }
    }

    // (C) tanh + pack
    float hv[2][4];
    union { u64 u; f16 h4[4]; } pk[2];
#pragma unroll
    for (int t2 = 0; t2 < 2; t2++) {
      f32x4 accv = t2 ? acc1 : acc0;
#pragma unroll
      for (int r = 0; r < 4; r++) {
        int m = q * 4 + r;
        float pre;
        if (is_l0) {
          float xwv = b0[t2];
#pragma unroll
          for (int d = 0; d < 6; d++) xwv += xs[m][d] * w0[t2][d];
          pre = accv[r] + xwv;
        } else {
          pre = accv[r] + (float)xwr[t2][r];
        }
        hv[t2][r] = tanhf(pre);
        pk[t2].h4[r] = (f16)hv[t2][r];
      }
    }

    // (D) publish h_t + arrive (layers 0..2 publish every t incl. 127 for the
    // epilogue transform; layer 3 only t<127, exactly like the baseline)
    const bool pub = (t < TSEQ - 1) || !is_top;
    if (pub) {
#pragma unroll
      for (int t2 = 0; t2 < 2; t2++) {
        int ng = ncol0 + t2 * 16 + l15;
        __hip_atomic_store(
            (u64*)&myhx[(((size_t)p * 64 + c) * 512 + ng) * 16 + q * 4],
            pk[t2].u, __ATOMIC_RELAXED, __HIP_MEMORY_SCOPE_AGENT);
      }
      __builtin_amdgcn_s_waitcnt(0);
      __syncthreads();
      if (tid == 0) {
        __hip_atomic_fetch_add(myctr, 1, __ATOMIC_RELAXED, __HIP_MEMORY_SCOPE_AGENT);
        if (!is_l0)
          __hip_atomic_store(ccp, t + 1, __ATOMIC_RELAXED, __HIP_MEMORY_SCOPE_AGENT);
      }
    }

    // (E) outputs
    if (is_top) {
#pragma unroll
      for (int t2 = 0; t2 < 2; t2++) {
        int ng = ncol0 + t2 * 16 + l15;
#pragma unroll
        for (int r = 0; r < 4; r++)
          out_f[((size_t)(row0 + q * 4 + r) * TSEQ + t) * 512 + ng] = hv[t2][r];
      }
    }
    if (t == TSEQ - 1) {
#pragma unroll
      for (int t2 = 0; t2 < 2; t2++) {
        int ng = ncol0 + t2 * 16 + l15;
#pragma unroll
        for (int r = 0; r < 4; r++)
          myhT[(size_t)(row0 + q * 4 + r) * 512 + ng] = pk[t2].h4[r];
      }
    }

    // (F) transform: xw_{t-1} = h_{t-1} @ Wih^{l+1} from As, publish to ring
    if (!is_top && t >= 1) {
      if (t >= 17)
        while (__hip_atomic_load(pcp, __ATOMIC_RELAXED, __HIP_MEMORY_SCOPE_AGENT) < t - 16)
          __builtin_amdgcn_s_sleep(1);
      f32x4 xa0 = zero, xa1 = zero;
#pragma unroll
      for (int kk = 0; kk < 16; kk++) {
        f16x8 a = *(const f16x8*)&As[l15 * 520 + kk * 32 + q * 8];
        f16x8 bv0 = *(const f16x8*)&Wt[(size_t)(ncol0 + l15) * 512 + kk * 32 + q * 8];
        f16x8 bv1 = *(const f16x8*)&Wt[(size_t)(ncol0 + 16 + l15) * 512 + kk * 32 + q * 8];
        xa0 = __builtin_amdgcn_mfma_f32_16x16x32_f16(a, bv0, xa0, 0, 0, 0);
        xa1 = __builtin_amdgcn_mfma_f32_16x16x32_f16(a, bv1, xa1, 0, 0, 0);
      }
      union { u64 u; f16 h4[4]; } qk[2];
#pragma unroll
      for (int r = 0; r < 4; r++) {
        qk[0].h4[r] = (f16)(xa0[r] + tb[0]);
        qk[1].h4[r] = (f16)(xa1[r] + tb[1]);
      }
      u64* rb = prng + ((size_t)c * 16 + ((t - 1) & 15)) * 2048;
      __hip_atomic_store(rb + (size_t)(ncol0 + l15) * 4 + q, qk[0].u, __ATOMIC_RELAXED, __HIP_MEMORY_SCOPE_AGENT);
      __hip_atomic_store(rb + (size_t)(ncol0 + 16 + l15) * 4 + q, qk[1].u, __ATOMIC_RELAXED, __HIP_MEMORY_SCOPE_AGENT);
      __builtin_amdgcn_s_waitcnt(0);
      __syncthreads();
      if (tid == 0)
        __hip_atomic_store(ppf, t, __ATOMIC_RELAXED, __HIP_MEMORY_SCOPE_AGENT);
    }

    if (t == TSEQ - 1) break;

    // (G) gather h_t, rebuild As
    if (tid == 0) {
      int target = 4 * (t + 1);
      while (__hip_atomic_load(myctr, __ATOMIC_RELAXED, __HIP_MEMORY_SCOPE_AGENT) < target)
        __builtin_amdgcn_s_sleep(1);
    }
    __syncthreads();
    {
      u64 v[8];
#pragma unroll
      for (int cc = 0; cc < 2; cc++) {
        int col = tid * 2 + cc;
        const u64* bp = (const u64*)&myhx[(((size_t)p * 64 + c) * 512 + col) * 16];
#pragma unroll
        for (int j = 0; j < 4; j++)
          v[cc * 4 + j] = __hip_atomic_load(bp + j, __ATOMIC_RELAXED, __HIP_MEMORY_SCOPE_AGENT);
      }
      union { u64 u[4]; f16 h[16]; } un0, un1;
      un0.u[0] = v[0]; un0.u[1] = v[1]; un0.u[2] = v[2]; un0.u[3] = v[3];
      un1.u[0] = v[4]; un1.u[1] = v[5]; un1.u[2] = v[6]; un1.u[3] = v[7];
#pragma unroll
      for (int k = 0; k < 16; k++) {
        union { f16 h2[2]; unsigned int u; } pw;
        pw.h2[0] = un0.h[k]; pw.h2[1] = un1.h[k];
        *(unsigned int*)&As[k * 520 + tid * 2] = pw.u;
      }
    }
    if (is_l0 && tid < 96)
      xs[tid / 6][tid % 6] = x[((size_t)(row0 + tid / 6) * TSEQ + (t + 1)) * 6 + tid % 6];
    __syncthreads();
  }

  // epilogue (layers 0..2): gather h_127 and publish xw_127 (slot 15)
  if (!is_top) {
    if (tid == 0) {
      while (__hip_atomic_load(myctr, __ATOMIC_RELAXED, __HIP_MEMORY_SCOPE_AGENT) < 4 * TSEQ)
        __builtin_amdgcn_s_sleep(1);
    }
    __syncthreads();
    {
      u64 v[8];
#pragma unroll
      for (int cc = 0; cc < 2; cc++) {
        int col = tid * 2 + cc;
        const u64* bp = (const u64*)&myhx[(((size_t)1 * 64 + c) * 512 + col) * 16];
#pragma unroll
        for (int j = 0; j < 4; j++)
          v[cc * 4 + j] = __hip_atomic_load(bp + j, __ATOMIC_RELAXED, __HIP_MEMORY_SCOPE_AGENT);
      }
      union { u64 u[4]; f16 h[16]; } un0, un1;
      un0.u[0] = v[0]; un0.u[1] = v[1]; un0.u[2] = v[2]; un0.u[3] = v[3];
      un1.u[0] = v[4]; un1.u[1] = v[5]; un1.u[2] = v[6]; un1.u[3] = v[7];
#pragma unroll
      for (int k = 0; k < 16; k++) {
        union { f16 h2[2]; unsigned int u; } pw;
        pw.h2[0] = un0.h[k]; pw.h2[1] = un1.h[k];
        *(unsigned int*)&As[k * 520 + tid * 2] = pw.u;
      }
    }
    __syncthreads();
    while (__hip_atomic_load(pcp, __ATOMIC_RELAXED, __HIP_MEMORY_SCOPE_AGENT) < TSEQ - 16)
      __builtin_amdgcn_s_sleep(1);
    const f32x4 zero = {0.f, 0.f, 0.f, 0.f};
    f32x4 xa0 = zero, xa1 = zero;
#pragma unroll
    for (int kk = 0; kk < 16; kk++) {
      f16x8 a = *(const f16x8*)&As[l15 * 520 + kk * 32 + q * 8];
      f16x8 bv0 = *(const f16x8*)&Wt[(size_t)(ncol0 + l15) * 512 + kk * 32 + q * 8];
      f16x8 bv1 = *(const f16x8*)&Wt[(size_t)(ncol0 + 16 + l15) * 512 + kk * 32 + q * 8];
      xa0 = __builtin_amdgcn_mfma_f32_16x16x32_f16(a, bv0, xa0, 0, 0, 0);
      xa1 = __builtin_amdgcn_mfma_f32_16x16x32_f16(a, bv1, xa1, 0, 0, 0);
    }
    union { u64 u; f16 h4[4]; } qk[2];
#pragma unroll
    for (int r = 0; r < 4; r++) {
      qk[0].h4[r] = (f16)(xa0[r] + tb[0]);
      qk[1].h4[r] = (f16)(xa1[r] + tb[1]);
    }
    u64* rb = prng + ((size_t)c * 16 + 15) * 2048;
    __hip_atomic_store(rb + (size_t)(ncol0 + l15) * 4 + q, qk[0].u, __ATOMIC_RELAXED, __HIP_MEMORY_SCOPE_AGENT);
    __hip_atomic_store(rb + (size_t)(ncol0 + 16 + l15) * 4 + q, qk[1].u, __ATOMIC_RELAXED, __HIP_MEMORY_SCOPE_AGENT);
    __builtin_amdgcn_s_waitcnt(0);
    __syncthreads();
    if (tid == 0)
      __hip_atomic_store(ppf, TSEQ, __ATOMIC_RELAXED, __HIP_MEMORY_SCOPE_AGENT);
  }
}

// ---------------- decoder (proven baseline, counter protocol) ----------------
__global__ __launch_bounds__(256) void k_dec_rec(
    const f16* __restrict__ Wih, const f16* __restrict__ Whh,
    const float* __restrict__ decB, const f16* __restrict__ hT,
    f16* __restrict__ hstate, f16* __restrict__ dec_out, int* __restrict__ ctr) {
  __shared__ f16 xb[16 * 520];
  __shared__ f16 hb[16 * 520];
  const int tid = threadIdx.x;
  const int w = tid >> 6, lane = tid & 63, q = lane >> 4, l15 = lane & 15;
  const int c = blockIdx.x >> 2, sub = blockIdx.x & 3;
  const int row0 = c * 16;
  const int ncol0 = sub * 128 + w * 32;
  int* myctr = ctr + c * 32;
  const size_t LSZ = (size_t)1024 * 512;

  auto load_rm = [&](f16* dst, const f16* src) {
#pragma unroll
    for (int i = 0; i < 4; i++) {
      int idx = tid + 256 * i; int m = idx >> 6, kc = idx & 63;
      *(f16x8*)&dst[m * 520 + kc * 8] = *(const f16x8*)&src[(size_t)(row0 + m) * 512 + kc * 8];
    }
  };
  auto load_cm = [&](f16* dst, int buf) {
    u64 v[8];
#pragma unroll
    for (int cc = 0; cc < 2; cc++) {
      int col = tid * 2 + cc;
      const u64* bp = (const u64*)&hstate[(((size_t)buf * 64 + c) * 512 + col) * 16];
#pragma unroll
      for (int j = 0; j < 4; j++)
        v[cc * 4 + j] = __hip_atomic_load(bp + j, __ATOMIC_RELAXED, __HIP_MEMORY_SCOPE_AGENT);
    }
    union { u64 u[4]; f16 h[16]; } un0, un1;
    un0.u[0] = v[0]; un0.u[1] = v[1]; un0.u[2] = v[2]; un0.u[3] = v[3];
    un1.u[0] = v[4]; un1.u[1] = v[5]; un1.u[2] = v[6]; un1.u[3] = v[7];
#pragma unroll
    for (int k = 0; k < 16; k++) {
      union { f16 h2[2]; unsigned int u; } pw;
      pw.h2[0] = un0.h[k]; pw.h2[1] = un1.h[k];
      *(unsigned int*)&dst[k * 520 + tid * 2] = pw.u;
    }
  };

  for (int s = 0; s < PRED; s++) {
    int wb = (s + 1) & 1, rb = s & 1;
    for (int l = 0; l < 4; l++) {
      const bool last = (s == PRED - 1) && (l == 3);
      if (l == 0) {
        if (s == 0) load_rm(xb, hT + 3 * LSZ);
        else load_cm(xb, rb * 4 + 3);
      } else {
        load_cm(xb, wb * 4 + (l - 1));
      }
      if (s == 0) load_rm(hb, hT + (size_t)l * LSZ);
      else load_cm(hb, rb * 4 + l);
      __syncthreads();

      const f32x4 zero = {0.f, 0.f, 0.f, 0.f};
      f32x4 acc0 = zero, acc1 = zero;
      const f16* Wl = Wih + (size_t)l * 512 * 512;
      const f16* Ul = Whh + (size_t)l * 512 * 512;
      int ng0 = ncol0 + l15, ng1 = ncol0 + 16 + l15;
#pragma unroll
      for (int kk = 0; kk < 16; kk++) {
        f16x8 a = *(const f16x8*)&xb[l15 * 520 + kk * 32 + q * 8];
        f16x8 bv0 = *(const f16x8*)&Wl[(size_t)ng0 * 512 + kk * 32 + q * 8];
        f16x8 bv1 = *(const f16x8*)&Wl[(size_t)ng1 * 512 + kk * 32 + q * 8];
        acc0 = __builtin_amdgcn_mfma_f32_16x16x32_f16(a, bv0, acc0, 0, 0, 0);
        acc1 = __builtin_amdgcn_mfma_f32_16x16x32_f16(a, bv1, acc1, 0, 0, 0);
      }
#pragma unroll
      for (int kk = 0; kk < 16; kk++) {
        f16x8 a = *(const f16x8*)&hb[l15 * 520 + kk * 32 + q * 8];
        f16x8 bv0 = *(const f16x8*)&Ul[(size_t)ng0 * 512 + kk * 32 + q * 8];
        f16x8 bv1 = *(const f16x8*)&Ul[(size_t)ng1 * 512 + kk * 32 + q * 8];
        acc0 = __builtin_amdgcn_mfma_f32_16x16x32_f16(a, bv0, acc0, 0, 0, 0);
        acc1 = __builtin_amdgcn_mfma_f32_16x16x32_f16(a, bv1, acc1, 0, 0, 0);
      }

      int obuf = wb * 4 + l;
      union { u64 u; f16 h4[4]; } pk[2];
#pragma unroll
      for (int t2 = 0; t2 < 2; t2++) {
        f32x4 accv = t2 ? acc1 : acc0;
        int ng = ncol0 + t2 * 16 + l15;
#pragma unroll
        for (int r = 0; r < 4; r++)
          pk[t2].h4[r] = (f16)tanhf(accv[r] + decB[l * 512 + ng]);
      }

      if (!last) {
#pragma unroll
        for (int t2 = 0; t2 < 2; t2++) {
          int ng = ncol0 + t2 * 16 + l15;
          __hip_atomic_store(
              (u64*)&hstate[(((size_t)obuf * 64 + c) * 512 + ng) * 16 + q * 4],
              pk[t2].u, __ATOMIC_RELAXED, __HIP_MEMORY_SCOPE_AGENT);
        }
        __builtin_amdgcn_s_waitcnt(0);
        __syncthreads();
        if (tid == 0)
          __hip_atomic_fetch_add(myctr, 1, __ATOMIC_RELAXED, __HIP_MEMORY_SCOPE_AGENT);
      }

      if (l == 3) {
#pragma unroll
        for (int t2 = 0; t2 < 2; t2++) {
          int ng = ncol0 + t2 * 16 + l15;
#pragma unroll
          for (int r = 0; r < 4; r++)
            dec_out[((size_t)(row0 + q * 4 + r) * PRED + s) * 512 + ng] = pk[t2].h4[r];
        }
      }

      if (!last) {
        if (tid == 0) {
          int target = 4 * (s * 4 + l + 1);
          while (__hip_atomic_load(myctr, __ATOMIC_RELAXED, __HIP_MEMORY_SCOPE_AGENT) < target)
            __builtin_amdgcn_s_sleep(1);
        }
        __syncthreads();
      }
    }
  }
}

// ---------------- final FC ----------------
__global__ __launch_bounds__(256) void k_fc(
    const f16* __restrict__ dec_out, const float* __restrict__ fcW,
    const float* __restrict__ fcb, float* __restrict__ out) {
  __shared__ float Wl[6 * 512];
  __shared__ float bl[8];
  int tid = threadIdx.x;
  for (int i = tid; i < 3072; i += 256) Wl[i] = fcW[i];
  if (tid < 6) bl[tid] = fcb[tid];
  __syncthreads();
  int g = blockIdx.x * 256 + tid;  // 0..10239
  const f16* row = dec_out + (size_t)g * 512;
  float acc[6] = {0, 0, 0, 0, 0, 0};
  for (int kc = 0; kc < 64; kc++) {
    f16x8 xv = *(const f16x8*)&row[kc * 8];
#pragma unroll
    for (int j = 0; j < 8; j++) {
      float xf = (float)xv[j];
#pragma unroll
      for (int o = 0; o < 6; o++) acc[o] += xf * Wl[o * 512 + kc * 8 + j];
    }
  }
#pragma unroll
  for (int o = 0; o < 6; o++) out[(size_t)g * 6 + o] = acc[o] + bl[o];
}

extern "C" void kernel_launch(void* const* d_in, const int* in_sizes, int n_in,
                              void* d_out, int out_size, void* d_ws, size_t ws_size,
                              hipStream_t stream) {
  const float* x      = (const float*)d_in[0];
  const float* Wih0   = (const float*)d_in[1];
  const float* eWih32 = (const float*)d_in[2];
  const float* eWhh32 = (const float*)d_in[3];
  const float* ebih   = (const float*)d_in[4];
  const float* ebhh   = (const float*)d_in[5];
  const float* dWih32 = (const float*)d_in[6];
  const float* dWhh32 = (const float*)d_in[7];
  const float* dbih   = (const float*)d_in[8];
  const float* dbhh   = (const float*)d_in[9];
  const float* fcW    = (const float*)d_in[10];
  const float* fcb    = (const float*)d_in[11];
  float* outp = (float*)d_out;

  char* ws = (char*)d_ws;
  size_t off = 0;
  auto alloc = [&](size_t bytes) { void* p = ws + off; off += (bytes + 255) & ~255ULL; return p; };
  f16* eWih   = (f16*)alloc((size_t)3 * 262144 * 2);
  f16* eWhh   = (f16*)alloc((size_t)4 * 262144 * 2);
  f16* dWih   = (f16*)alloc((size_t)4 * 262144 * 2);
  f16* dWhh   = (f16*)alloc((size_t)4 * 262144 * 2);
  float* encB = (float*)alloc(2048 * 4);
  float* decB = (float*)alloc(2048 * 4);
  f16* hT     = (f16*)alloc((size_t)4 * 1024 * 512 * 2);
  f16* hstate = (f16*)alloc((size_t)8 * 1024 * 512 * 2);
  f16* hx     = (f16*)alloc((size_t)4 * 2 * 64 * 8192 * 2);
  f16* xwring = (f16*)alloc((size_t)3 * 64 * 16 * 8192 * 2);
  f16* dec_o  = (f16*)alloc((size_t)1024 * 10 * 512 * 2);
  // sync block: encoder ctr (4*64*32) + dec ctr (64*32) + pf + cp
  int* ctrE   = (int*)alloc(4 * 64 * 32 * 4);
  int* ctrD   = (int*)alloc(64 * 32 * 4);
  int* pfA    = (int*)alloc(3 * 64 * 4 * 8 * 4);
  int* cpA    = (int*)alloc(3 * 64 * 4 * 8 * 4);

  size_t syncsz = (char*)(cpA + 3 * 64 * 4 * 8) - (char*)ctrE;
  hipMemsetAsync(ctrE, 0, syncsz, stream);

  k_cvt<<<512, 256, 0, stream>>>(eWih32, eWih, 3 * 262144);
  k_cvt<<<512, 256, 0, stream>>>(eWhh32, eWhh, 4 * 262144);
  k_cvt<<<512, 256, 0, stream>>>(dWih32, dWih, 4 * 262144);
  k_cvt<<<512, 256, 0, stream>>>(dWhh32, dWhh, 4 * 262144);
  k_bias<<<8, 256, 0, stream>>>(ebih, ebhh, encB, 2048);
  k_bias<<<8, 256, 0, stream>>>(dbih, dbhh, decB, 2048);

  // wavefront-pipelined encoder: all 4 layers in one launch
  k_enc_wave<<<1024, 256, 0, stream>>>(x, Wih0, eWih, encB, eWhh, outp, hT, hx,
                                       xwring, ctrE, pfA, cpA);
  k_dec_rec<<<256, 256, 0, stream>>>(dWih, dWhh, decB, hT, hstate, dec_o, ctrD);
  k_fc<<<40, 256, 0, stream>>>(dec_o, fcW, fcb, outp + (size_t)1024 * 128 * 512);
}